// Round 12
// baseline (107.684 us; speedup 1.0000x reference)
//
#include <hip/hip_runtime.h>
#include <math.h>

#define B_  2
#define T_  2048
#define D_  512
#define H_  8
#define HD_ 64
#define QKVS (3*D_)   // 1536

typedef __bf16 bf16x8 __attribute__((ext_vector_type(8)));
typedef float  f32x4  __attribute__((ext_vector_type(4)));

__device__ inline unsigned short f2bf(float f) {   // RN-even fp32->bf16
  unsigned int u = __float_as_uint(f);
  return (unsigned short)((u + 0x7FFFu + ((u >> 16) & 1u)) >> 16);
}
__device__ inline unsigned int pack2bf(float lo, float hi) {
  return (unsigned int)f2bf(lo) | ((unsigned int)f2bf(hi) << 16);
}

// ---------------------------------------------------------------------------
// Fused cast fp32 -> bf16 for x, w_qkv, w_out in one launch (float4 units).
// ---------------------------------------------------------------------------
__global__ void cast_all(const float* __restrict__ x,
                         const float* __restrict__ wq,
                         const float* __restrict__ wo,
                         unsigned short* __restrict__ xb,
                         unsigned short* __restrict__ wqb,
                         unsigned short* __restrict__ wob) {
  const int n_x  = (B_ * T_ * D_) / 4;
  const int n_wq = (QKVS * D_) / 4;
  const int n_wo = (D_ * D_) / 4;
  int i = blockIdx.x * blockDim.x + threadIdx.x;
  const float* src; unsigned short* dst; int off;
  if (i < n_x)                    { src = x;  dst = xb;  off = i; }
  else if (i < n_x + n_wq)        { src = wq; dst = wqb; off = i - n_x; }
  else if (i < n_x + n_wq + n_wo) { src = wo; dst = wob; off = i - n_x - n_wq; }
  else return;
  float4 v = ((const float4*)src)[off];
  ushort4 o;
  o.x = f2bf(v.x); o.y = f2bf(v.y); o.z = f2bf(v.z); o.w = f2bf(v.w);
  ((ushort4*)dst)[off] = o;
}

// ---------------------------------------------------------------------------
// MFMA bf16 GEMM (NT), 64x64 tile, BK=64 (two 32-K panels per barrier round).
// 4 waves (2x2), each 32x32 = 2x2 accs. LDS 16 KB -> high occupancy:
// GEMM1 grid 1536 = 6 blocks/CU, GEMM2 grid 512 = 2/CU, so per-CU
// co-resident blocks hide each other's staging drains (R11 showed round
// count is exhausted; the remaining GEMM cost is exposed drain latency
// at 1-3 blocks/CU).
// Staging map per 32-K panel: thread t -> row=t>>2, k=(t&3)*8; LDS offset
// = t*16 B (DMA lane-order exact, same proven scheme as 128-tile version).
// ---------------------------------------------------------------------------
template<int BF16OUT>
__global__ __launch_bounds__(256, 4)
void gemm_nt_64(const unsigned short* __restrict__ A,
                const unsigned short* __restrict__ Bw,
                const float* __restrict__ bias, void* __restrict__ Cv,
                int M, int N, int K) {
  __shared__ short Asd[2][64 * 32];   // 2 x 4 KB
  __shared__ short Bsd[2][64 * 32];   // 2 x 4 KB

  const int tid = threadIdx.x;
  const int w   = tid >> 6;
  const int l   = tid & 63;
  const int wr  = w >> 1;           // wave row 0..1 (32-row halves)
  const int wc  = w & 1;            // wave col 0..1 (32-col halves)
  const int q   = l >> 4;
  const int ml  = l & 15;
  const int srow = tid >> 2;        // staging row 0..63
  const int kch  = (tid & 3) * 8;   // staging k-offset (halfs)

  const int rowbase = blockIdx.y * 64;
  const int colbase = blockIdx.x * 64;

  f32x4 acc[2][2] = {};

  for (int k0 = 0; k0 < K; k0 += 64) {
    __syncthreads();
    #pragma unroll
    for (int pnl = 0; pnl < 2; ++pnl) {
      const int kp = k0 + pnl * 32;
      const unsigned short* ga =
          A + (size_t)(rowbase + srow) * K + kp + kch;
      __builtin_amdgcn_global_load_lds(
          (const __attribute__((address_space(1))) void*)ga,
          (__attribute__((address_space(3))) void*)&Asd[pnl][w * 512],
          16, 0, 0);
      const unsigned short* gb =
          Bw + (size_t)(colbase + srow) * K + kp + kch;
      __builtin_amdgcn_global_load_lds(
          (const __attribute__((address_space(1))) void*)gb,
          (__attribute__((address_space(3))) void*)&Bsd[pnl][w * 512],
          16, 0, 0);
    }
    __syncthreads();

    #pragma unroll
    for (int pnl = 0; pnl < 2; ++pnl) {
      bf16x8 af[2], bfr[2];
      #pragma unroll
      for (int mi = 0; mi < 2; ++mi)
        af[mi] = *(const bf16x8*)&Asd[pnl][(wr * 32 + mi * 16 + ml) * 32 + q * 8];
      #pragma unroll
      for (int ni = 0; ni < 2; ++ni)
        bfr[ni] = *(const bf16x8*)&Bsd[pnl][(wc * 32 + ni * 16 + ml) * 32 + q * 8];
      #pragma unroll
      for (int mi = 0; mi < 2; ++mi)
        #pragma unroll
        for (int ni = 0; ni < 2; ++ni)
          acc[mi][ni] = __builtin_amdgcn_mfma_f32_16x16x32_bf16(
              af[mi], bfr[ni], acc[mi][ni], 0, 0, 0);
    }
  }

  #pragma unroll
  for (int mi = 0; mi < 2; ++mi) {
    #pragma unroll
    for (int ni = 0; ni < 2; ++ni) {
      const int col = colbase + wc * 32 + ni * 16 + ml;
      const float bv = bias[col];
      #pragma unroll
      for (int r = 0; r < 4; ++r) {
        const int row = rowbase + wr * 32 + mi * 16 + q * 4 + r;
        const float val = acc[mi][ni][r] + bv;
        if (BF16OUT)
          ((unsigned short*)Cv)[(size_t)row * N + col] = f2bf(val);
        else
          ((float*)Cv)[(size_t)row * N + col] = val;
      }
    }
  }
}

// ---------------------------------------------------------------------------
// Residue-class flash attention, 64-query stripes, 64-key rounds (R10 exact):
// heavy-first dispatch, prefetch pipeline, per-16-key-tile skip.
// ---------------------------------------------------------------------------
__global__ __launch_bounds__(256)
void attn_flash4(const unsigned short* __restrict__ qkv,
                 const int* __restrict__ periods,
                 unsigned short* __restrict__ ao) {
  const int bh = blockIdx.x, slot = 62 - blockIdx.y;   // heavy-first
  int p = periods[bh]; if (p < 1) p = 1;
  const int g  = slot / p;
  const int r  = slot - g * p;
  const int L  = (T_ - 1 - r) / p + 1;   // tokens in this residue class
  const int q0 = g << 6;                 // stripe base (t-space)
  if (q0 >= L) return;
  const int b = bh >> 3, h = bh & 7;
  const int Lrem = L - q0;               // >= 1
  const int Nkb  = min(L, q0 + 64);      // keys needed by the whole block

  const int tid  = threadIdx.x;
  const int w    = tid >> 6;             // wave 0..3
  const int lane = tid & 63;
  const int Q = lane >> 4, c = lane & 15;

  __shared__ __align__(16) unsigned short Qs[64 * 72];  // 9216 B
  __shared__ __align__(16) unsigned short Ks[64 * 72];  // 9216 B
  __shared__ __align__(16) unsigned short Vt[64 * 72];  // 9216 B, [d][key]

  const size_t rowb = (size_t)b * T_ * QKVS + (size_t)h * HD_;

  // ---- stage Q stripe (64 rows x 64 halfs): 32 B per thread ----
  {
    const int u = tid >> 2, ch4 = (tid & 3) * 16;
    const int t = q0 + min(u, Lrem - 1);            // clamp (dup row, masked)
    const unsigned short* gq = qkv + rowb + (size_t)(r + t * p) * QKVS + ch4;
    int4 v0 = ((const int4*)gq)[0];
    int4 v1 = ((const int4*)gq)[1];
    *(int4*)&Qs[u * 72 + ch4 + 0] = v0;
    *(int4*)&Qs[u * 72 + ch4 + 8] = v1;
  }
  __syncthreads();
  bf16x8 qf[2];                          // B-frag: B[k=d=Q*8+j(+32)][n=q=c]
  qf[0] = *(const bf16x8*)&Qs[(w * 16 + c) * 72 + Q * 8];
  qf[1] = *(const bf16x8*)&Qs[(w * 16 + c) * 72 + Q * 8 + 32];

  const int qb      = w * 16;            // wave's query offset in stripe
  const int nqw     = min(16, Lrem - qb);// <=0 -> inactive wave (barriers only)
  const int qglob   = q0 + qb + c;       // this lane's query t-index
  const int mylastk = q0 + qb + 15;      // last key this wave can need

  float m_run = -3.0e38f, l_run = 0.f;
  f32x4 o[4] = {};
  const size_t kb = rowb + D_;
  const size_t vb = rowb + 2 * D_;

  // staging assignments (256 threads, 64-key tiles)
  const int krow = tid >> 2, koff = (tid & 3) * 16;     // K: 2x16B/thread
  const int vkey = tid & 63, vd0 = (tid >> 6) * 8;      // V: 2x16B/thread

  // ---- prefetch round 0 ----
  int4 kp0, kp1, vp0, vp1;
  {
    const int tk = min(krow, Nkb - 1);
    const int tv = min(vkey, Nkb - 1);
    const unsigned short* gk = qkv + kb + (size_t)(r + tk * p) * QKVS + koff;
    const unsigned short* gv = qkv + vb + (size_t)(r + tv * p) * QKVS;
    kp0 = ((const int4*)gk)[0];
    kp1 = ((const int4*)gk)[1];
    vp0 = *(const int4*)(gv + vd0);
    vp1 = *(const int4*)(gv + vd0 + 32);
  }

  for (int k0 = 0; k0 < Nkb; k0 += 64) {
    __syncthreads();                     // prev round's frag reads complete
    // ---- commit prefetched K (row-major) + V (transposed) ----
    {
      *(int4*)&Ks[krow * 72 + koff + 0] = kp0;
      *(int4*)&Ks[krow * 72 + koff + 8] = kp1;
      unsigned short vh0[8], vh1[8];
      *(int4*)vh0 = vp0;
      *(int4*)vh1 = vp1;
      #pragma unroll
      for (int j = 0; j < 8; ++j) {
        Vt[(vd0 + j) * 72 + vkey]      = vh0[j];
        Vt[(vd0 + 32 + j) * 72 + vkey] = vh1[j];
      }
    }
    __syncthreads();                     // LDS valid

    // ---- issue next round's global loads (hide behind compute) ----
    if (k0 + 64 < Nkb) {
      const int tk = min(k0 + 64 + krow, Nkb - 1);
      const int tv = min(k0 + 64 + vkey, Nkb - 1);
      const unsigned short* gk = qkv + kb + (size_t)(r + tk * p) * QKVS + koff;
      const unsigned short* gv = qkv + vb + (size_t)(r + tv * p) * QKVS;
      kp0 = ((const int4*)gk)[0];
      kp1 = ((const int4*)gk)[1];
      vp0 = *(const int4*)(gv + vd0);
      vp1 = *(const int4*)(gv + vd0 + 32);
    }

    if (nqw > 0 && k0 <= mylastk) {
      // ---- S^T tiles (4 x 16 keys), per-tile skip ----
      float pvv[16];
      float tmax = -3.0e38f;
      #pragma unroll
      for (int mt = 0; mt < 4; ++mt) {
        if (k0 + mt * 16 <= mylastk) {
          bf16x8 a0 = *(const bf16x8*)&Ks[(mt * 16 + c) * 72 + Q * 8];
          bf16x8 a1 = *(const bf16x8*)&Ks[(mt * 16 + c) * 72 + Q * 8 + 32];
          f32x4 s = {};
          s = __builtin_amdgcn_mfma_f32_16x16x32_bf16(a0, qf[0], s, 0, 0, 0);
          s = __builtin_amdgcn_mfma_f32_16x16x32_bf16(a1, qf[1], s, 0, 0, 0);
          #pragma unroll
          for (int rg = 0; rg < 4; ++rg) {
            const int kk = k0 + mt * 16 + Q * 4 + rg;   // key t-index
            float v = s[rg] * 0.125f;                   // 1/sqrt(HD)
            v = (kk <= qglob) ? v : -3.0e38f;
            pvv[mt * 4 + rg] = v;
            tmax = fmaxf(tmax, v);
          }
        } else {
          #pragma unroll
          for (int rg = 0; rg < 4; ++rg) pvv[mt * 4 + rg] = -3.0e38f;
        }
      }

      // ---- online softmax per column (q = c) ----
      tmax = fmaxf(tmax, __shfl_xor(tmax, 16));
      tmax = fmaxf(tmax, __shfl_xor(tmax, 32));
      const float m_new = fmaxf(m_run, tmax);
      const float alpha = __expf(m_run - m_new);
      float tsum = 0.f;
      #pragma unroll
      for (int i = 0; i < 16; ++i) {
        pvv[i] = __expf(pvv[i] - m_new);
        tsum += pvv[i];
      }
      tsum += __shfl_xor(tsum, 16);
      tsum += __shfl_xor(tsum, 32);
      l_run = l_run * alpha + tsum;
      m_run = m_new;

      // ---- P^T -> B-operand frags per 32-key chunk ----
      bf16x8 pb[2];
      const int sq2 = (Q & 1) << 1;
      #pragma unroll
      for (int kc = 0; kc < 2; ++kc) {
        unsigned int pk0[2], pk1[2];
        pk0[0] = pack2bf(pvv[kc * 8 + 0], pvv[kc * 8 + 1]);
        pk0[1] = pack2bf(pvv[kc * 8 + 2], pvv[kc * 8 + 3]);
        pk1[0] = pack2bf(pvv[kc * 8 + 4], pvv[kc * 8 + 5]);
        pk1[1] = pack2bf(pvv[kc * 8 + 6], pvv[kc * 8 + 7]);
        int dw[4];
        #pragma unroll
        for (int d = 0; d < 4; ++d) {
          const int src = ((sq2 + (d >> 1)) << 4) + c;
          const int v0 = __shfl((int)pk0[d & 1], src);
          const int v1 = __shfl((int)pk1[d & 1], src);
          dw[d] = (Q >= 2) ? v1 : v0;
        }
        int4 bi = make_int4(dw[0], dw[1], dw[2], dw[3]);
        pb[kc] = *(bf16x8*)&bi;
      }

      // ---- O^T += V^T . P^T  (2 key-chunks x 4 d-chunks) ----
      #pragma unroll
      for (int ch = 0; ch < 4; ++ch)
        #pragma unroll
        for (int t2 = 0; t2 < 4; ++t2) o[ch][t2] *= alpha;
      #pragma unroll
      for (int kc = 0; kc < 2; ++kc) {
        if (k0 + kc * 32 <= mylastk) {
          #pragma unroll
          for (int ch = 0; ch < 4; ++ch) {
            bf16x8 af =
                *(const bf16x8*)&Vt[(ch * 16 + c) * 72 + kc * 32 + Q * 8];
            o[ch] = __builtin_amdgcn_mfma_f32_16x16x32_bf16(af, pb[kc], o[ch],
                                                            0, 0, 0);
          }
        }
      }
    }
  }

  // ---- epilogue: O[q][d] = O^T[d][q] / l ----
  if (nqw > 0 && c < nqw) {
    const float invl = 1.f / l_run;
    const int tok = r + (q0 + qb + c) * p;
    unsigned int* dst =
        (unsigned int*)(ao + (size_t)(b * T_ + tok) * D_ + h * HD_);
    #pragma unroll
    for (int ch = 0; ch < 4; ++ch)
      #pragma unroll
      for (int rp = 0; rp < 2; ++rp) {
        const int dhalf = ch * 16 + Q * 4 + rp * 2;   // even
        dst[dhalf >> 1] =
            pack2bf(o[ch][rp * 2] * invl, o[ch][rp * 2 + 1] * invl);
      }
  }
}

// ---------------------------------------------------------------------------
extern "C" void kernel_launch(void* const* d_in, const int* in_sizes, int n_in,
                              void* d_out, int out_size, void* d_ws, size_t ws_size,
                              hipStream_t stream) {
  const float* x      = (const float*)d_in[0];   // (B,T,D)
  const int*   period = (const int*)  d_in[1];   // (B,H)
  const float* w_qkv  = (const float*)d_in[2];   // (3D, D)
  const float* b_qkv  = (const float*)d_in[3];   // (3D,)
  const float* w_out  = (const float*)d_in[4];   // (D, D)
  const float* b_out  = (const float*)d_in[5];   // (D,)
  float* out = (float*)d_out;                    // (B,T,D)

  const int M = B_ * T_;                         // 4096

  // ws layout (MB): xb[0,4) wqb[4,5.5) wob[5.5,6) qkvb[6,18)
  char* ws = (char*)d_ws;
  unsigned short* xb   = (unsigned short*)(ws);
  unsigned short* wqb  = (unsigned short*)(ws + (size_t)M * D_ * 2);
  unsigned short* wob  = (unsigned short*)(ws + (size_t)M * D_ * 2
                                              + (size_t)QKVS * D_ * 2);
  unsigned short* qkvb = (unsigned short*)(ws + (size_t)M * D_ * 2
                                              + (size_t)QKVS * D_ * 2
                                              + (size_t)D_ * D_ * 2);
  unsigned short* aob  = xb;   // alias: x_bf16 dead after GEMM1

  // fused input casts
  {
    const int n4 = (M * D_ + QKVS * D_ + D_ * D_) / 4;
    cast_all<<<dim3((n4 + 255) / 256), dim3(256), 0, stream>>>(
        x, w_qkv, w_out, xb, wqb, wob);
  }

  // 1) QKV projection -> bf16 token-major qkvb (64x64 tile, grid 24x64 = 1536
  //    = 6 blocks/CU: co-resident blocks hide staging drains)
  gemm_nt_64<1><<<dim3(QKVS / 64, M / 64), dim3(256), 0, stream>>>(
      xb, wqb, b_qkv, qkvb, M, QKVS, D_);

  // 2) residue-class flash attention (64-query stripes, 64-key rounds) -> aob
  attn_flash4<<<dim3(16, 63), dim3(256), 0, stream>>>(qkvb, period, aob);

  // 3) output projection -> fp32 out (64x64 tile, grid 8x64 = 512 = 2/CU)
  gemm_nt_64<0><<<dim3(D_ / 64, M / 64), dim3(256), 0, stream>>>(
      aob, wob, b_out, out, M, D_, D_);
}